// Round 1
// baseline (9947.266 us; speedup 1.0000x reference)
//
#include <hip/hip_runtime.h>

#define N_NODES 100000
#define N_EDGES 1600000

__device__ __forceinline__ bool idx_is64(const int* flag) { return *flag == 0; }

__device__ __forceinline__ int load_idx(const void* p, int e, bool is64) {
  if (is64) return (int)((const long long*)p)[e];
  return ((const int*)p)[e];
}

// OR all odd 32-bit words of the first N_EDGES words of src.
// int64 indices (< 2^31) -> all high words zero -> flag stays 0.
// int32 indices -> odd words are real random indices -> flag becomes 1.
__global__ void detect_k(const unsigned* __restrict__ w, int* __restrict__ flag) {
  unsigned acc = 0;
  for (int i = blockIdx.x * blockDim.x + threadIdx.x; i < N_EDGES / 2;
       i += gridDim.x * blockDim.x)
    acc |= w[2 * i + 1];
  unsigned long long m = __ballot(acc != 0);
  if ((threadIdx.x & 63) == 0 && m != 0ULL) atomicOr(flag, 1);
}

__global__ void degree_k(const void* __restrict__ src, const void* __restrict__ dst,
                         const int* __restrict__ flag, float* __restrict__ ns,
                         float* __restrict__ nd) {
  int e = blockIdx.x * blockDim.x + threadIdx.x;
  if (e >= N_EDGES) return;
  bool is64 = idx_is64(flag);
  atomicAdd(&ns[load_idx(src, e, is64)], 1.0f);
  atomicAdd(&nd[load_idx(dst, e, is64)], 1.0f);
}

__global__ void norm_k(float* ns, float* nd) {
  int i = blockIdx.x * blockDim.x + threadIdx.x;
  if (i >= N_NODES) return;
  ns[i] = rsqrtf(fmaxf(ns[i], 1.0f));
  nd[i] = rsqrtf(fmaxf(nd[i], 1.0f));
}

// H[n][c] = sum_k xform(X[n][k]) * W[k][c]
// FIRST:  xform = X * ns[n]
// !FIRST: xform = relu(X * nd[n] + bprev[k]) * ns[n]   (fused prev-layer epilogue)
template <int OUT, bool FIRST>
__global__ __launch_bounds__(256) void gemm_k(
    const float* __restrict__ X, const float* __restrict__ W,
    const float* __restrict__ bprev, const float* __restrict__ ns,
    const float* __restrict__ nd, float* __restrict__ H) {
  constexpr int CG = OUT / 4;        // col groups (4 cols each)
  constexpr int RG = 256 / CG;       // row groups (4 rows each)
  constexpr int ROWS = RG * 4;
  constexpr int RG_PER_WAVE = 64 / CG;
  constexpr int XPAD = (RG_PER_WAVE > 2) ? 4 : 0;  // stagger banks when >2 bcast addrs/wave
  constexpr int XST = 128 + XPAD;
  __shared__ float Ws[128 * OUT];
  __shared__ float xs[ROWS * XST];
  const int t = threadIdx.x;
  for (int i = t; i < 128 * OUT; i += 256) Ws[i] = W[i];
  const int base = blockIdx.x * ROWS;
  for (int i = t; i < ROWS * 128; i += 256) {
    int r = i >> 7, k = i & 127;
    int n = base + r;
    float v = 0.0f;
    if (n < N_NODES) {
      v = X[(size_t)n * 128 + k];
      if constexpr (FIRST) {
        v *= ns[n];
      } else {
        v = fmaxf(v * nd[n] + bprev[k], 0.0f) * ns[n];
      }
    }
    xs[r * XST + k] = v;
  }
  __syncthreads();
  const int cg = t % CG, rg = t / CG;
  const int c0 = cg * 4, r0 = rg * 4;
  float acc[4][4] = {};
  for (int k = 0; k < 128; k += 4) {
    float4 a[4], b[4];
#pragma unroll
    for (int i = 0; i < 4; i++) a[i] = *(const float4*)&xs[(r0 + i) * XST + k];
#pragma unroll
    for (int j = 0; j < 4; j++) b[j] = *(const float4*)&Ws[(k + j) * OUT + c0];
#pragma unroll
    for (int i = 0; i < 4; i++) {
      acc[i][0] += a[i].x * b[0].x + a[i].y * b[1].x + a[i].z * b[2].x + a[i].w * b[3].x;
      acc[i][1] += a[i].x * b[0].y + a[i].y * b[1].y + a[i].z * b[2].y + a[i].w * b[3].y;
      acc[i][2] += a[i].x * b[0].z + a[i].y * b[1].z + a[i].z * b[2].z + a[i].w * b[3].z;
      acc[i][3] += a[i].x * b[0].w + a[i].y * b[1].w + a[i].z * b[2].w + a[i].w * b[3].w;
    }
  }
#pragma unroll
  for (int i = 0; i < 4; i++) {
    int n = base + r0 + i;
    if (n < N_NODES) {
      float4 o = make_float4(acc[i][0], acc[i][1], acc[i][2], acc[i][3]);
      *(float4*)&H[(size_t)n * OUT + c0] = o;
    }
  }
}

// agg[dst[e]][:] += h[src[e]][:]  -- F/4 threads per edge, float4 gather, 4 f32 atomics
template <int F>
__global__ __launch_bounds__(256) void agg_k(const float* __restrict__ h,
                                             const void* __restrict__ src,
                                             const void* __restrict__ dst,
                                             const int* __restrict__ flag,
                                             float* __restrict__ agg) {
  constexpr int PER = F / 4;
  long long tid = (long long)blockIdx.x * 256 + threadIdx.x;
  int e = (int)(tid / PER);
  if (e >= N_EDGES) return;
  int q = (int)(tid % PER);
  bool is64 = idx_is64(flag);
  int s = load_idx(src, e, is64);
  int d = load_idx(dst, e, is64);
  float4 v = *(const float4*)(h + (size_t)s * F + q * 4);
  float* o = agg + (size_t)d * F + q * 4;
  atomicAdd(o + 0, v.x);
  atomicAdd(o + 1, v.y);
  atomicAdd(o + 2, v.z);
  atomicAdd(o + 3, v.w);
}

__global__ void epilogue_k(const float* __restrict__ agg, const float* __restrict__ nd,
                           const float* __restrict__ b, float* __restrict__ out) {
  int tid = blockIdx.x * blockDim.x + threadIdx.x;
  if (tid >= N_NODES * 16) return;
  int n = tid >> 4, q = tid & 15;
  float4 v = *(const float4*)(agg + (size_t)n * 64 + q * 4);
  float s = nd[n];
  float4 bb = *(const float4*)(b + q * 4);
  float4 o = make_float4(v.x * s + bb.x, v.y * s + bb.y, v.z * s + bb.z, v.w * s + bb.w);
  *(float4*)(out + (size_t)n * 64 + q * 4) = o;
}

extern "C" void kernel_launch(void* const* d_in, const int* in_sizes, int n_in,
                              void* d_out, int out_size, void* d_ws, size_t ws_size,
                              hipStream_t stream) {
  const float* in_feat = (const float*)d_in[0];
  const void* src = d_in[1];
  const void* dst = d_in[2];
  const float* W1 = (const float*)d_in[3];
  const float* b1 = (const float*)d_in[4];
  const float* W2 = (const float*)d_in[5];
  const float* b2 = (const float*)d_in[6];
  const float* W3 = (const float*)d_in[7];
  const float* b3 = (const float*)d_in[8];
  const float* W4 = (const float*)d_in[9];
  const float* b4 = (const float*)d_in[10];
  float* out = (float*)d_out;

  char* ws = (char*)d_ws;
  float* h = (float*)(ws + 0);                     // N*128 f32 = 51.2 MB
  float* agg = (float*)(ws + 51200000);            // N*128 f32 = 51.2 MB
  float* ns = (float*)(ws + 102400000);            // N f32
  float* nd = (float*)(ws + 102800000);            // N f32
  int* flag = (int*)(ws + 103200000);              // 4 B

  hipMemsetAsync(flag, 0, 4, stream);
  hipMemsetAsync(ns, 0, (size_t)N_NODES * 4, stream);
  hipMemsetAsync(nd, 0, (size_t)N_NODES * 4, stream);
  detect_k<<<256, 256, 0, stream>>>((const unsigned*)src, flag);
  degree_k<<<(N_EDGES + 255) / 256, 256, 0, stream>>>(src, dst, flag, ns, nd);
  norm_k<<<(N_NODES + 255) / 256, 256, 0, stream>>>(ns, nd);

  // Layer 1
  gemm_k<128, true><<<(N_NODES + 31) / 32, 256, 0, stream>>>(in_feat, W1, nullptr, ns, nd, h);
  hipMemsetAsync(agg, 0, (size_t)N_NODES * 128 * 4, stream);
  agg_k<128><<<(N_EDGES * 32) / 256, 256, 0, stream>>>(h, src, dst, flag, agg);

  // Layer 2 (fuses relu(agg*nd+b1)*ns into x-load)
  gemm_k<128, false><<<(N_NODES + 31) / 32, 256, 0, stream>>>(agg, W2, b1, ns, nd, h);
  hipMemsetAsync(agg, 0, (size_t)N_NODES * 128 * 4, stream);
  agg_k<128><<<(N_EDGES * 32) / 256, 256, 0, stream>>>(h, src, dst, flag, agg);

  // Layer 3
  gemm_k<128, false><<<(N_NODES + 31) / 32, 256, 0, stream>>>(agg, W3, b2, ns, nd, h);
  hipMemsetAsync(agg, 0, (size_t)N_NODES * 128 * 4, stream);
  agg_k<128><<<(N_EDGES * 32) / 256, 256, 0, stream>>>(h, src, dst, flag, agg);

  // Layer 4 (OUT=64)
  gemm_k<64, false><<<(N_NODES + 63) / 64, 256, 0, stream>>>(agg, W4, b3, ns, nd, h);
  hipMemsetAsync(agg, 0, (size_t)N_NODES * 64 * 4, stream);
  agg_k<64><<<(N_EDGES * 16) / 256, 256, 0, stream>>>(h, src, dst, flag, agg);
  epilogue_k<<<(N_NODES * 16 + 255) / 256, 256, 0, stream>>>(agg, nd, b4, out);
}

// Round 2
// 999.831 us; speedup vs baseline: 9.9489x; 9.9489x over previous
//
#include <hip/hip_runtime.h>

#define N_NODES 100000
#define N_EDGES 1600000
#define NBLK_SCAN ((N_NODES + 1023) / 1024)   // 98

__device__ __forceinline__ bool idx_is64(const int* flag) { return *flag == 0; }

__device__ __forceinline__ int load_idx(const void* p, int e, bool is64) {
  if (is64) return (int)((const long long*)p)[e];
  return ((const int*)p)[e];
}

// OR all odd 32-bit words of src. int64 (<2^31) -> all zero -> flag stays 0.
__global__ void detect_k(const unsigned* __restrict__ w, int* __restrict__ flag) {
  unsigned acc = 0;
  for (int i = blockIdx.x * blockDim.x + threadIdx.x; i < N_EDGES / 2;
       i += gridDim.x * blockDim.x)
    acc |= w[2 * i + 1];
  unsigned long long m = __ballot(acc != 0);
  if ((threadIdx.x & 63) == 0 && m != 0ULL) atomicOr(flag, 1);
}

__global__ void hist_k(const void* __restrict__ src, const void* __restrict__ dst,
                       const int* __restrict__ flag, int* __restrict__ cs,
                       int* __restrict__ cd) {
  int e = blockIdx.x * blockDim.x + threadIdx.x;
  if (e >= N_EDGES) return;
  bool is64 = idx_is64(flag);
  atomicAdd(&cs[load_idx(src, e, is64)], 1);
  atomicAdd(&cd[load_idx(dst, e, is64)], 1);
}

// counts (int, in-place) -> rsqrt(max(deg,1)) (float)
__global__ void norm_k(float* ns, float* nd) {
  int i = blockIdx.x * blockDim.x + threadIdx.x;
  if (i >= N_NODES) return;
  int a = ((const int*)ns)[i], b = ((const int*)nd)[i];
  ns[i] = rsqrtf((float)(a > 1 ? a : 1));
  nd[i] = rsqrtf((float)(b > 1 ? b : 1));
}

// ---- exclusive scan of cnt_dst[100000] -> row_ptr ----
__global__ void scan1_k(const int* __restrict__ cnt, int* __restrict__ row_ptr,
                        int* __restrict__ blksum) {
  __shared__ int sm[256];
  int blk = blockIdx.x, t = threadIdx.x;
  int base = blk * 1024 + t * 4;
  int v[4], s = 0;
#pragma unroll
  for (int j = 0; j < 4; j++) {
    int i = base + j;
    v[j] = (i < N_NODES) ? cnt[i] : 0;
    s += v[j];
  }
  sm[t] = s;
  __syncthreads();
  for (int off = 1; off < 256; off <<= 1) {
    int x = (t >= off) ? sm[t - off] : 0;
    __syncthreads();
    sm[t] += x;
    __syncthreads();
  }
  if (t == 255) blksum[blk] = sm[255];
  int run = sm[t] - s;  // exclusive prefix within block
#pragma unroll
  for (int j = 0; j < 4; j++) {
    int i = base + j;
    if (i < N_NODES) row_ptr[i] = run;
    run += v[j];
  }
}

__global__ void scan2_k(const int* __restrict__ blksum, int* __restrict__ blkoff) {
  if (threadIdx.x == 0 && blockIdx.x == 0) {
    int run = 0;
    for (int b = 0; b < NBLK_SCAN; b++) {
      blkoff[b] = run;
      run += blksum[b];
    }
  }
}

__global__ void scan3_k(int* __restrict__ row_ptr, const int* __restrict__ blkoff) {
  int i = blockIdx.x * blockDim.x + threadIdx.x;
  if (i < N_NODES) row_ptr[i] += blkoff[i >> 10];
  if (i == 0) row_ptr[N_NODES] = N_EDGES;
}

__global__ void scatter_k(const void* __restrict__ src, const void* __restrict__ dst,
                          const int* __restrict__ flag, const int* __restrict__ row_ptr,
                          int* __restrict__ cursor, int* __restrict__ ss) {
  int e = blockIdx.x * blockDim.x + threadIdx.x;
  if (e >= N_EDGES) return;
  bool is64 = idx_is64(flag);
  int d = load_idx(dst, e, is64);
  int pos = row_ptr[d] + atomicAdd(&cursor[d], 1);
  ss[pos] = load_idx(src, e, is64);
}

// agg[n][:] = sum over incoming edges of h[src][:]   (no atomics)
template <int F>
__global__ __launch_bounds__(256) void agg_csr_k(const float* __restrict__ h,
                                                 const int* __restrict__ row_ptr,
                                                 const int* __restrict__ ss,
                                                 float* __restrict__ agg) {
  constexpr int L = F / 4;  // lanes per node
  int g = threadIdx.x / L, lane = threadIdx.x % L;
  int n = blockIdx.x * (256 / L) + g;
  if (n >= N_NODES) return;
  int beg = row_ptr[n], end = row_ptr[n + 1];
  float4 acc = make_float4(0.f, 0.f, 0.f, 0.f);
  int e = beg;
  for (; e + 3 < end; e += 4) {
    int s0 = ss[e], s1 = ss[e + 1], s2 = ss[e + 2], s3 = ss[e + 3];
    float4 v0 = *(const float4*)&h[(size_t)s0 * F + lane * 4];
    float4 v1 = *(const float4*)&h[(size_t)s1 * F + lane * 4];
    float4 v2 = *(const float4*)&h[(size_t)s2 * F + lane * 4];
    float4 v3 = *(const float4*)&h[(size_t)s3 * F + lane * 4];
    acc.x += v0.x + v1.x + v2.x + v3.x;
    acc.y += v0.y + v1.y + v2.y + v3.y;
    acc.z += v0.z + v1.z + v2.z + v3.z;
    acc.w += v0.w + v1.w + v2.w + v3.w;
  }
  for (; e < end; e++) {
    int s = ss[e];
    float4 v = *(const float4*)&h[(size_t)s * F + lane * 4];
    acc.x += v.x; acc.y += v.y; acc.z += v.z; acc.w += v.w;
  }
  *(float4*)&agg[(size_t)n * F + lane * 4] = acc;
}

// H[n][c] = sum_k xform(X[n][k]) * W[k][c]
template <int OUT, bool FIRST>
__global__ __launch_bounds__(256) void gemm_k(
    const float* __restrict__ X, const float* __restrict__ W,
    const float* __restrict__ bprev, const float* __restrict__ ns,
    const float* __restrict__ nd, float* __restrict__ H) {
  constexpr int CG = OUT / 4;
  constexpr int RG = 256 / CG;
  constexpr int ROWS = RG * 4;
  constexpr int RG_PER_WAVE = 64 / CG;
  constexpr int XPAD = (RG_PER_WAVE > 2) ? 4 : 0;
  constexpr int XST = 128 + XPAD;
  __shared__ float Ws[128 * OUT];
  __shared__ float xs[ROWS * XST];
  const int t = threadIdx.x;
  for (int i = t; i < 128 * OUT; i += 256) Ws[i] = W[i];
  const int base = blockIdx.x * ROWS;
  for (int i = t; i < ROWS * 128; i += 256) {
    int r = i >> 7, k = i & 127;
    int n = base + r;
    float v = 0.0f;
    if (n < N_NODES) {
      v = X[(size_t)n * 128 + k];
      if constexpr (FIRST) {
        v *= ns[n];
      } else {
        v = fmaxf(v * nd[n] + bprev[k], 0.0f) * ns[n];
      }
    }
    xs[r * XST + k] = v;
  }
  __syncthreads();
  const int cg = t % CG, rg = t / CG;
  const int c0 = cg * 4, r0 = rg * 4;
  float acc[4][4] = {};
  for (int k = 0; k < 128; k += 4) {
    float4 a[4], b[4];
#pragma unroll
    for (int i = 0; i < 4; i++) a[i] = *(const float4*)&xs[(r0 + i) * XST + k];
#pragma unroll
    for (int j = 0; j < 4; j++) b[j] = *(const float4*)&Ws[(k + j) * OUT + c0];
#pragma unroll
    for (int i = 0; i < 4; i++) {
      acc[i][0] += a[i].x * b[0].x + a[i].y * b[1].x + a[i].z * b[2].x + a[i].w * b[3].x;
      acc[i][1] += a[i].x * b[0].y + a[i].y * b[1].y + a[i].z * b[2].y + a[i].w * b[3].y;
      acc[i][2] += a[i].x * b[0].z + a[i].y * b[1].z + a[i].z * b[2].z + a[i].w * b[3].z;
      acc[i][3] += a[i].x * b[0].w + a[i].y * b[1].w + a[i].z * b[2].w + a[i].w * b[3].w;
    }
  }
#pragma unroll
  for (int i = 0; i < 4; i++) {
    int n = base + r0 + i;
    if (n < N_NODES) {
      float4 o = make_float4(acc[i][0], acc[i][1], acc[i][2], acc[i][3]);
      *(float4*)&H[(size_t)n * OUT + c0] = o;
    }
  }
}

__global__ void epilogue_k(const float* __restrict__ agg, const float* __restrict__ nd,
                           const float* __restrict__ b, float* __restrict__ out) {
  int tid = blockIdx.x * blockDim.x + threadIdx.x;
  if (tid >= N_NODES * 16) return;
  int n = tid >> 4, q = tid & 15;
  float4 v = *(const float4*)(agg + (size_t)n * 64 + q * 4);
  float s = nd[n];
  float4 bb = *(const float4*)(b + q * 4);
  float4 o = make_float4(v.x * s + bb.x, v.y * s + bb.y, v.z * s + bb.z, v.w * s + bb.w);
  *(float4*)(out + (size_t)n * 64 + q * 4) = o;
}

extern "C" void kernel_launch(void* const* d_in, const int* in_sizes, int n_in,
                              void* d_out, int out_size, void* d_ws, size_t ws_size,
                              hipStream_t stream) {
  const float* in_feat = (const float*)d_in[0];
  const void* src = d_in[1];
  const void* dst = d_in[2];
  const float* W1 = (const float*)d_in[3];
  const float* b1 = (const float*)d_in[4];
  const float* W2 = (const float*)d_in[5];
  const float* b2 = (const float*)d_in[6];
  const float* W3 = (const float*)d_in[7];
  const float* b3 = (const float*)d_in[8];
  const float* W4 = (const float*)d_in[9];
  const float* b4 = (const float*)d_in[10];
  float* out = (float*)d_out;

  // --- workspace (proven >= 103.2 MB) ---
  char* ws = (char*)d_ws;
  float* h   = (float*)(ws + 0);            // 51.2 MB
  float* agg = (float*)(ws + 51200000);     // 51.2 MB
  float* ns  = (float*)(ws + 102400000);    // 400 KB (ints during hist)
  float* nd  = (float*)(ws + 102800000);    // 400 KB (ints during hist)
  int* flag  = (int*)(ws + 103200000);      // 4 B

  // --- CSR scratch in d_out (fully overwritten by epilogue at the end) ---
  char* ob = (char*)d_out;
  int* sorted_src = (int*)(ob + 0);          // 6.4 MB
  int* row_ptr    = (int*)(ob + 6400000);    // 400,004 B
  int* cursor     = (int*)(ob + 6800004);    // 400,000 B
  int* blksum     = (int*)(ob + 7200004);    // 392 B
  int* blkoff     = (int*)(ob + 7200500);    // 392 B

  hipMemsetAsync(flag, 0, 4, stream);
  hipMemsetAsync(ns, 0, (size_t)N_NODES * 4, stream);
  hipMemsetAsync(nd, 0, (size_t)N_NODES * 4, stream);
  hipMemsetAsync(cursor, 0, (size_t)N_NODES * 4, stream);

  detect_k<<<256, 256, 0, stream>>>((const unsigned*)src, flag);
  hist_k<<<(N_EDGES + 255) / 256, 256, 0, stream>>>(src, dst, flag, (int*)ns, (int*)nd);
  // scan over cnt_dst (stored in nd buffer, still int) BEFORE norm_k converts it
  scan1_k<<<NBLK_SCAN, 256, 0, stream>>>((const int*)nd, row_ptr, blksum);
  scan2_k<<<1, 64, 0, stream>>>(blksum, blkoff);
  scan3_k<<<(N_NODES + 255) / 256, 256, 0, stream>>>(row_ptr, blkoff);
  norm_k<<<(N_NODES + 255) / 256, 256, 0, stream>>>(ns, nd);
  scatter_k<<<(N_EDGES + 255) / 256, 256, 0, stream>>>(src, dst, flag, row_ptr,
                                                       cursor, sorted_src);

  // Layer 1
  gemm_k<128, true><<<(N_NODES + 31) / 32, 256, 0, stream>>>(in_feat, W1, nullptr, ns, nd, h);
  agg_csr_k<128><<<(N_NODES * 32 + 255) / 256, 256, 0, stream>>>(h, row_ptr, sorted_src, agg);
  // Layer 2 (relu(agg*nd+b1)*ns fused into x-load)
  gemm_k<128, false><<<(N_NODES + 31) / 32, 256, 0, stream>>>(agg, W2, b1, ns, nd, h);
  agg_csr_k<128><<<(N_NODES * 32 + 255) / 256, 256, 0, stream>>>(h, row_ptr, sorted_src, agg);
  // Layer 3
  gemm_k<128, false><<<(N_NODES + 31) / 32, 256, 0, stream>>>(agg, W3, b2, ns, nd, h);
  agg_csr_k<128><<<(N_NODES * 32 + 255) / 256, 256, 0, stream>>>(h, row_ptr, sorted_src, agg);
  // Layer 4 (OUT=64)
  gemm_k<64, false><<<(N_NODES + 63) / 64, 256, 0, stream>>>(agg, W4, b3, ns, nd, h);
  agg_csr_k<64><<<(N_NODES * 16 + 255) / 256, 256, 0, stream>>>(h, row_ptr, sorted_src, agg);
  epilogue_k<<<(N_NODES * 16 + 255) / 256, 256, 0, stream>>>(agg, nd, b4, out);
}